// Round 14
// baseline (137.498 us; speedup 1.0000x reference)
//
#include <hip/hip_runtime.h>

#define IMG_H 512
#define IMG_W 512
#define N_IMG 24                          // B*C
#define NPIX (N_IMG * IMG_H * IMG_W)      // 6291456
#define TH 8                              // center rows per block
#define LR (TH + 4)                       // 12 staged rows
#define PLANE (LR * IMG_W)                // 6144 floats = 24576 B per plane
#define BLOCK 256
#define NBLOCKS (N_IMG * IMG_H / TH)      // 1536

__device__ __forceinline__ int reflect_row(int x) {   // PAD=2 reflect
    int a = x < 0 ? -x : x;
    int b = 2 * IMG_H - 2 - a;
    return a < b ? a : b;
}

// Direct global->LDS DMA, 16B/lane: no VGPR round-trip, stays in flight
// until our explicit vmcnt wait. LDS dest = uniform base + lane*16.
__device__ __forceinline__ void load_lds16(const float* g, float* l) {
    __builtin_amdgcn_global_load_lds(
        (const __attribute__((address_space(1))) void*)g,
        (__attribute__((address_space(3))) void*)l, 16, 0, 0);
}

__global__ void census_init(unsigned int* __restrict__ ws) {
    ws[0] = 0u;
    ws[1] = 0u;
}

// 5 census combos of neighbor-row r vs one center row (wave-uniform cnt).
#define JBLOCK(PC, GC, SKIPR)                                        \
    {                                                                \
        cnt += __popcll(__ballot(pv0 < PC) ^ __ballot(gv0 < GC));    \
        cnt += __popcll(__ballot(pv1 < PC) ^ __ballot(gv1 < GC));    \
        if (r != (SKIPR))                                            \
            cnt += __popcll(__ballot(pv2 < PC) ^ __ballot(gv2 < GC));\
        cnt += __popcll(__ballot(pv3 < PC) ^ __ballot(gv3 < GC));    \
        cnt += __popcll(__ballot(pv4 < PC) ^ __ballot(gv4 < GC));    \
    }

__global__ __launch_bounds__(BLOCK) void census_main(
    const float* __restrict__ pred, const float* __restrict__ gt,
    float* __restrict__ out, unsigned int* __restrict__ ws)
{
    __shared__ float lds[2 * PLANE];      // [plane][row][col], 48 KB
    __shared__ int wave_sums[BLOCK / 64];

    const int tid  = threadIdx.x;
    const int lane = tid & 63;
    const int wave = tid >> 6;
    const int b    = blockIdx.x;
    const int img  = b >> 6;              // 64 row-groups per image
    const int hb   = (b & 63) * TH;       // first center row of tile

    const float* __restrict__ pimg = pred + (size_t)img * IMG_H * IMG_W;
    const float* __restrict__ gimg = gt   + (size_t)img * IMG_H * IMG_W;

    // ---- stage 12 rows x 512 cols x 2 planes via global_load_lds ----
    // wave w stages rows 3w..3w+2; per row: 2 chunks x 2 planes = 4 DMAs.
    #pragma unroll
    for (int q = 0; q < 3; ++q) {
        const int i  = wave * 3 + q;          // staged row 0..11
        const int gy = reflect_row(hb - 2 + i);
        const float* prow = pimg + gy * IMG_W;
        const float* grow = gimg + gy * IMG_W;
        #pragma unroll
        for (int c = 0; c < 2; ++c) {         // 256-float chunks
            const int go = (c << 8) + (lane << 2);   // lane's 4 floats
            const int lo = i * IMG_W + (c << 8);     // uniform LDS base
            load_lds16(prow + go, &lds[lo]);
            load_lds16(grow + go, &lds[PLANE + lo]);
        }
    }
    asm volatile("s_waitcnt vmcnt(0)" ::: "memory");
    __syncthreads();

    // ---- wave-ballot census, rolled loops, separate planes ----
    int cnt = 0;                          // wave-uniform

    #pragma unroll 1
    for (int k = 0; k < 4; ++k) {
        const int u     = wave * 4 + k;   // 0..15
        const int rbase = (u & 1) * 4;    // row-group base
        const int cc    = (u >> 1) * 64 + lane;   // center col

        // reflect-clamped shifted cols (NAMED scalars)
        const int cx0 = abs(cc - 2);
        const int cx1 = abs(cc - 1);
        const int cx2 = cc;
        const int t3  = cc + 1;
        const int cx3 = min(t3, 1022 - t3);
        const int t4  = cc + 2;
        const int cx4 = min(t4, 1022 - t4);

        // center values: staged rows rbase+2 .. rbase+5
        const int cb = rbase * IMG_W + cc;
        const float pct0 = lds[cb + 2 * IMG_W], gct0 = lds[PLANE + cb + 2 * IMG_W];
        const float pct1 = lds[cb + 3 * IMG_W], gct1 = lds[PLANE + cb + 3 * IMG_W];
        const float pct2 = lds[cb + 4 * IMG_W], gct2 = lds[PLANE + cb + 4 * IMG_W];
        const float pct3 = lds[cb + 5 * IMG_W], gct3 = lds[PLANE + cb + 5 * IMG_W];

        #pragma unroll 1
        for (int r = 0; r < 8; ++r) {     // staged rows rbase..rbase+7
            const int ro = (rbase + r) * IMG_W;
            const float pv0 = lds[ro + cx0], gv0 = lds[PLANE + ro + cx0];
            const float pv1 = lds[ro + cx1], gv1 = lds[PLANE + ro + cx1];
            const float pv2 = lds[ro + cx2], gv2 = lds[PLANE + ro + cx2];
            const float pv3 = lds[ro + cx3], gv3 = lds[PLANE + ro + cx3];
            const float pv4 = lds[ro + cx4], gv4 = lds[PLANE + ro + cx4];

            if (r <= 4)           JBLOCK(pct0, gct0, 2)
            if (r >= 1 && r <= 5) JBLOCK(pct1, gct1, 3)
            if (r >= 2 && r <= 6) JBLOCK(pct2, gct2, 4)
            if (r >= 3)           JBLOCK(pct3, gct3, 5)
        }
    }

    // ---- block reduction: cnt is wave-uniform ----
    if (lane == 0) wave_sums[wave] = cnt;
    __syncthreads();

    if (tid == 0) {
        int total = wave_sums[0] + wave_sums[1] + wave_sums[2] + wave_sums[3];
        atomicAdd(&ws[0], (unsigned int)total);
        __threadfence();
        unsigned int r = atomicAdd(&ws[1], 1u);
        if (r == (unsigned int)(NBLOCKS - 1)) {
            unsigned int tot = atomicAdd(&ws[0], 0u);
            out[0] = (float)((double)tot / (double)NPIX);
        }
    }
}

extern "C" void kernel_launch(void* const* d_in, const int* in_sizes, int n_in,
                              void* d_out, int out_size, void* d_ws, size_t ws_size,
                              hipStream_t stream) {
    const float* pred = (const float*)d_in[0];
    const float* gt   = (const float*)d_in[1];
    float* out        = (float*)d_out;
    unsigned int* ws  = (unsigned int*)d_ws;

    census_init<<<1, 1, 0, stream>>>(ws);
    census_main<<<NBLOCKS, BLOCK, 0, stream>>>(pred, gt, out, ws);
}